// Round 9
// baseline (171.097 us; speedup 1.0000x reference)
//
#include <hip/hip_runtime.h>
#include <math.h>

#define HIDDEN 128
#define MAXBUK 512
#define E1_TPB 256
#define E1_EPT 4
#define E1_EPB (E1_TPB * E1_EPT)   // 1024 edges per block
#define E1_PPB (E1_EPB * 2)        // 2048 pairs per block

// W1P layout v9: [t 0..32)][kh 0..2)][s 0..8)][18]
//   idx = t*288 + kh*144 + s*18 + ii   (ii 0..15, 2 pad)
// 16 distinct b128 addrs per wave: s-stride 18 -> banks {0,18,4,22,8,26,12,30},
// kh-stride 144 -> +16 -> the other 16 banks. All 32 banks covered exactly
// 2-way (2 lanes/bank is free). Lanes differing only in group bits b4b5 read
// identical addresses (broadcast).
#define W1P_T_STRIDE  288
#define W1P_KH_STRIDE 144
#define W1P_S_STRIDE  18
#define W1P_FLOATS    (32 * W1P_T_STRIDE)   // 9216 floats = 36864 B

// ---- cross-lane helpers ----------------------------------------------------
__device__ __forceinline__ float dpp_xor1(float v) {
    int t = __builtin_amdgcn_update_dpp(0, __float_as_int(v),
                                        0xB1, 0xF, 0xF, true); // quad_perm [1,0,3,2]
    return __int_as_float(t);
}
__device__ __forceinline__ float dpp_xor2(float v) {
    int t = __builtin_amdgcn_update_dpp(0, __float_as_int(v),
                                        0x4E, 0xF, 0xF, true); // quad_perm [2,3,0,1]
    return __int_as_float(t);
}
__device__ __forceinline__ float xor4_add(float v) {   // lane ^ 4
    int t = __builtin_amdgcn_ds_swizzle(__float_as_int(v), 0x101F);
    return v + __int_as_float(t);
}
__device__ __forceinline__ float xor8_add(float v) {   // lane ^ 8
    int t = __builtin_amdgcn_ds_swizzle(__float_as_int(v), 0x201F);
    return v + __int_as_float(t);
}

// fast gelu: 0.5x(1+erf(x/sqrt2)), A&S 7.1.26, |erf err|<=2e-7
__device__ __forceinline__ float gelu_fast(float x) {
    const float u  = x * 0.70710678118654752f;
    const float au = fabsf(u);
    const float t  = __builtin_amdgcn_rcpf(fmaf(0.3275911f, au, 1.0f));
    float poly = fmaf(1.061405429f, t, -1.453152027f);
    poly = fmaf(poly, t, 1.421413741f);
    poly = fmaf(poly, t, -0.284496736f);
    poly = fmaf(poly, t, 0.254829592f);
    poly *= t;
    const float e = __expf(-au * au);
    const float erfabs = fmaf(-poly, e, 1.0f);
    const float erfv = copysignf(erfabs, u);
    return 0.5f * x * (1.0f + erfv);
}

// ---------------------------------------------------------------------------
// Pack + prep fused.
// ---------------------------------------------------------------------------
__global__ __launch_bounds__(256) void pack_kernel(
    const float* __restrict__ h, const float* __restrict__ rain,
    const float* __restrict__ W1,
    float* __restrict__ packed, float* __restrict__ netT,
    float* __restrict__ W1P, unsigned* __restrict__ counters, int N)
{
    const int tid = threadIdx.x;
    const int b = blockIdx.x;
    if (b < 16) {
        for (int i = tid; i < 512; i += 256) {
            const int k  = 4 * b + (i >> 7);     // 0..63
            const int hh = i & 127;
            const int s  = hh >> 4, ii = hh & 15;
            const int kh = k >> 5, t = k & 31;
            W1P[t * W1P_T_STRIDE + kh * W1P_KH_STRIDE + s * W1P_S_STRIDE + ii]
                = W1[hh * 64 + k];
        }
        if (b == 0)
            for (int i = tid; i < MAXBUK; i += 256) counters[i] = 0u;
    }
    const int n = b * blockDim.x + tid;
    if (n >= N) return;
    *reinterpret_cast<float2*>(&packed[4 * n]) = make_float2(h[n], h[N + n]);
    *reinterpret_cast<float2*>(&netT[2 * n])   = make_float2(rain[n], rain[N + n]);
}

// ---------------------------------------------------------------------------
// Node kernel v9: 16-lane groups = (kh 2) x (s 8) own 4 rows.
//  zr[4][16] = 64 VGPRs (below compiler's 128 comfort zone -> truly resident).
//  4R threads -> ~6 waves/SIMD. W chunk (16 floats) reused across 4 rows.
//  Per t: quad transpose (xor1/xor2) + ds_swizzle xor4 -> one gelu per lane.
//  kh halves joined once at the end with xor8.
// ---------------------------------------------------------------------------
__global__ __launch_bounds__(256) void node_kernel(
    const float* __restrict__ z,     // [R][128]
    const float* __restrict__ W1P,   // [32][2][8][18]
    const float* __restrict__ b1, const float* __restrict__ W2,
    const float* __restrict__ b2, const float* __restrict__ Wa,
    const float* __restrict__ ba,
    float* __restrict__ packed, float* __restrict__ areas,
    int N, int R)
{
    __shared__ float w1s[W1P_FLOATS];   // 36864 B
    __shared__ float bw[128];           // interleaved (b1[k], W2[k])
    __shared__ float was[128];

    const int tid = threadIdx.x;
    for (int i = tid; i < W1P_FLOATS; i += 256) w1s[i] = W1P[i];
    if (tid < 64)       { bw[2 * tid] = b1[tid]; bw[2 * tid + 1] = W2[tid]; }
    else if (tid < 192) was[tid - 64] = Wa[tid - 64];
    __syncthreads();

    const int s  = tid & 7;            // h-slice (16 floats)
    const int kh = (tid >> 3) & 1;     // k-half (32 of 64 cols)
    const int r0 = ((blockIdx.x * 256 + tid) >> 4) * 4;  // group's 4 rows
    if (r0 >= R) return;               // R % 4 == 0: no per-row guards

    // 4 rows x 16-float slice -> 64 VGPRs (static indices only)
    float zr[4][16];
#pragma unroll
    for (int j = 0; j < 4; ++j) {
        const float4* zp = reinterpret_cast<const float4*>(
            z + (size_t)(r0 + j) * HIDDEN + s * 16);
#pragma unroll
        for (int i = 0; i < 4; ++i) {
            const float4 v = zp[i];
            zr[j][4 * i + 0] = v.x; zr[j][4 * i + 1] = v.y;
            zr[j][4 * i + 2] = v.z; zr[j][4 * i + 3] = v.w;
        }
    }

    const bool e1 = (s & 1) == 0;
    const bool e2 = (s & 2) == 0;

    float cf = 0.f;                     // row (s&3), this k-half
    const float* __restrict__ wbase =
        &w1s[kh * W1P_KH_STRIDE + s * W1P_S_STRIDE];
    const float* __restrict__ bwbase = &bw[kh * 64];

#pragma unroll 2
    for (int t = 0; t < 32; ++t) {
        const float* __restrict__ wk = wbase + t * W1P_T_STRIDE;
        float p0 = 0.f, p1 = 0.f, p2 = 0.f, p3 = 0.f;
#pragma unroll
        for (int i = 0; i < 4; ++i) {
            const float4 w = *reinterpret_cast<const float4*>(&wk[4 * i]);
            p0 = fmaf(zr[0][4 * i + 0], w.x, p0);
            p1 = fmaf(zr[1][4 * i + 0], w.x, p1);
            p2 = fmaf(zr[2][4 * i + 0], w.x, p2);
            p3 = fmaf(zr[3][4 * i + 0], w.x, p3);
            p0 = fmaf(zr[0][4 * i + 1], w.y, p0);
            p1 = fmaf(zr[1][4 * i + 1], w.y, p1);
            p2 = fmaf(zr[2][4 * i + 1], w.y, p2);
            p3 = fmaf(zr[3][4 * i + 1], w.y, p3);
            p0 = fmaf(zr[0][4 * i + 2], w.z, p0);
            p1 = fmaf(zr[1][4 * i + 2], w.z, p1);
            p2 = fmaf(zr[2][4 * i + 2], w.z, p2);
            p3 = fmaf(zr[3][4 * i + 2], w.z, p3);
            p0 = fmaf(zr[0][4 * i + 3], w.w, p0);
            p1 = fmaf(zr[1][4 * i + 3], w.w, p1);
            p2 = fmaf(zr[2][4 * i + 3], w.w, p2);
            p3 = fmaf(zr[3][4 * i + 3], w.w, p3);
        }
        // quad transpose-reduce: lane ends with row (s&3) over its slice-quad
        const float a   = e1 ? p0 : p1, b = e1 ? p1 : p0;
        const float ulo = a + dpp_xor1(b);
        const float c   = e1 ? p2 : p3, d = e1 ? p3 : p2;
        const float uhi = c + dpp_xor1(d);
        const float a2  = e2 ? ulo : uhi, b2v = e2 ? uhi : ulo;
        const float x4  = a2 + dpp_xor2(b2v);
        const float x8  = xor4_add(x4);             // join slice-quads: full dot

        const float2 bwk = *reinterpret_cast<const float2*>(&bwbase[2 * t]);
        const float g = gelu_fast(x8 + bwk.x);
        cf = fmaf(g, bwk.y, cf);                    // one gelu+fma per lane
    }
    const float cf_full = xor8_add(cf);             // combine k-halves

    // areas: 16-float slice dot, same reduction (kh-redundant)
    float q0 = 0.f, q1 = 0.f, q2 = 0.f, q3 = 0.f;
#pragma unroll
    for (int i = 0; i < 16; ++i) {
        const float wv = was[s * 16 + i];
        q0 = fmaf(zr[0][i], wv, q0);
        q1 = fmaf(zr[1][i], wv, q1);
        q2 = fmaf(zr[2][i], wv, q2);
        q3 = fmaf(zr[3][i], wv, q3);
    }
    const float aa  = e1 ? q0 : q1, ab = e1 ? q1 : q0;
    const float alo = aa + dpp_xor1(ab);
    const float ac  = e1 ? q2 : q3, adt = e1 ? q3 : q2;
    const float ahi = ac + dpp_xor1(adt);
    const float aa2 = e2 ? alo : ahi, ab2 = e2 ? ahi : alo;
    const float a4  = aa2 + dpp_xor2(ab2);
    const float ad  = xor4_add(a4);                 // row (s&3) z@Wa

    if ((tid & 12) == 0) {                          // kh==0 && s<4
        const int r = r0 + (s & 3);
        const float cv   = 1.0f / (1.0f + expf(-(cf_full + b2[0])));
        const float adv  = ad + ba[0];
        const float area = fmaxf(adv, 0.f) + log1pf(expf(-fabsf(adv)));
        const int bb = (r >= N) ? 1 : 0;
        const int n = r - bb * N;
        packed[4 * n + 2 + bb] = cv;
        areas[r] = area;
    }
}

// ---------------------------------------------------------------------------
// E1: per-edge flows + in-block counting-sort of (node, +/-f0,f1) pairs into
// per-bucket global segments (bucket = node>>8). ~196 int atomics per block.
// ---------------------------------------------------------------------------
__global__ __launch_bounds__(E1_TPB) void edge_bin_kernel(
    const int* __restrict__ eidx,      // [2][E]
    const float* __restrict__ packed,  // [N][4] = h0,h1,c0,c1
    float* __restrict__ flows,         // [2][E]
    unsigned* __restrict__ keysG,      // [nbuk][cap]
    float2* __restrict__ valsG,        // [nbuk][cap]
    unsigned* __restrict__ counters,   // [nbuk]
    int E, int nbuk, int cap)
{
    __shared__ unsigned hist[MAXBUK];
    __shared__ unsigned base[MAXBUK];
    __shared__ unsigned gbase[MAXBUK];
    __shared__ unsigned scan[E1_TPB];
    __shared__ unsigned skey[E1_PPB];
    __shared__ float2   sval[E1_PPB];

    const int tid = threadIdx.x;
    const int e0  = blockIdx.x * E1_EPB;

    for (int i = tid; i < nbuk; i += E1_TPB) hist[i] = 0;
    __syncthreads();

    unsigned mykey[2 * E1_EPT];
    unsigned myoff[2 * E1_EPT];
    float2   myval[2 * E1_EPT];

#pragma unroll
    for (int j = 0; j < E1_EPT; ++j) {
        const int e = e0 + j * E1_TPB + tid;
        unsigned kd = 0xFFFFFFFFu, ks = 0xFFFFFFFFu;
        float2 vd = make_float2(0.f, 0.f), vs = vd;
        if (e < E) {
            const int s = eidx[e];
            const int d = eidx[E + e];
            const float4 ps = *reinterpret_cast<const float4*>(&packed[4 * s]);
            const float4 pd = *reinterpret_cast<const float4*>(&packed[4 * d]);

            float dh = ps.x - pd.x;
            float sg = (dh > 0.f) ? 1.f : ((dh < 0.f) ? -1.f : 0.f);
            float f0 = ps.z * sg * sqrtf(fabsf(dh) + 1e-6f);
            f0 = fminf(fmaxf(f0, -10.0f), 10.0f);

            dh = ps.y - pd.y;
            sg = (dh > 0.f) ? 1.f : ((dh < 0.f) ? -1.f : 0.f);
            float f1 = ps.w * sg * sqrtf(fabsf(dh) + 1e-6f);
            f1 = fminf(fmaxf(f1, -10.0f), 10.0f);

            flows[e] = f0;
            flows[(size_t)E + e] = f1;

            kd = (unsigned)d; vd = make_float2(f0, f1);
            ks = (unsigned)s; vs = make_float2(-f0, -f1);
        }
        mykey[2 * j]     = kd; myval[2 * j]     = vd;
        mykey[2 * j + 1] = ks; myval[2 * j + 1] = vs;
        if (kd != 0xFFFFFFFFu) {
            myoff[2 * j]     = atomicAdd(&hist[kd >> 8], 1u);
            myoff[2 * j + 1] = atomicAdd(&hist[ks >> 8], 1u);
        }
    }
    __syncthreads();

    // Hillis-Steele inclusive scan of hist (nbuk <= 256)
    const unsigned hv = (tid < nbuk) ? hist[tid] : 0u;
    scan[tid] = hv;
    __syncthreads();
    for (int off = 1; off < E1_TPB; off <<= 1) {
        unsigned t = (tid >= off) ? scan[tid - off] : 0u;
        __syncthreads();
        scan[tid] += t;
        __syncthreads();
    }
    if (tid < nbuk) {
        base[tid] = scan[tid] - hv;
        if (hv > 0) gbase[tid] = atomicAdd(&counters[tid], hv);
    }
    __syncthreads();

#pragma unroll
    for (int j = 0; j < 2 * E1_EPT; ++j) {
        const unsigned k = mykey[j];
        if (k != 0xFFFFFFFFu) {
            const unsigned idx = base[k >> 8] + myoff[j];
            skey[idx] = k;
            sval[idx] = myval[j];
        }
    }
    __syncthreads();

    const int tot = 2 * min(E1_EPB, E - e0);
    for (int i = tid; i < tot; i += E1_TPB) {
        const unsigned k = skey[i];
        const unsigned bb = k >> 8;
        const unsigned pos = gbase[bb] + ((unsigned)i - base[bb]);
        if (pos < (unsigned)cap) {
            keysG[(size_t)bb * cap + pos] = k;
            valsG[(size_t)bb * cap + pos] = sval[i];
        }
    }
}

// ---------------------------------------------------------------------------
// E2: one block (512 thr) per bucket; FOUR LDS accumulator copies cut
// same-node atomic serialization. Fused h-update. No global f32 atomics.
// ---------------------------------------------------------------------------
__global__ __launch_bounds__(512) void bucket_reduce_kernel(
    const unsigned* __restrict__ keysG, const float2* __restrict__ valsG,
    const unsigned* __restrict__ counters,
    const float* __restrict__ h, const float* __restrict__ rain,
    const float* __restrict__ areas,
    float* __restrict__ hnew, int N, int cap)
{
    __shared__ float accx[4][256], accy[4][256];   // 8 KB
    const int tid = threadIdx.x;
    const int b = blockIdx.x;
    const int q = tid >> 7;                        // 4 groups of 128
    {
        float* fx = &accx[0][0];
        float* fy = &accy[0][0];
        fx[tid] = 0.f; fx[tid + 512] = 0.f;
        fy[tid] = 0.f; fy[tid + 512] = 0.f;
    }
    __syncthreads();

    const int cnt = min((int)counters[b], cap);
    const unsigned* __restrict__ sk = keysG + (size_t)b * cap;
    const float2*  __restrict__  sv = valsG + (size_t)b * cap;
    for (int i = tid; i < cnt; i += 512) {
        const unsigned k = sk[i];
        const float2 v2 = sv[i];
        const int loc = (int)(k & 255u);
        atomicAdd(&accx[q][loc], v2.x);
        atomicAdd(&accy[q][loc], v2.y);
    }
    __syncthreads();

    if (tid < 256) {
        const int n = (b << 8) + tid;
        if (n < N) {
            const float net0 = rain[n]     + ((accx[0][tid] + accx[1][tid])
                                           + (accx[2][tid] + accx[3][tid]));
            const float net1 = rain[N + n] + ((accy[0][tid] + accy[1][tid])
                                           + (accy[2][tid] + accy[3][tid]));
            float dh0 = 300.0f * net0 / (areas[n] + 1e-6f);
            dh0 = fminf(fmaxf(dh0, -1.0f), 1.0f);
            hnew[n] = h[n] + dh0;
            float dh1 = 300.0f * net1 / (areas[N + n] + 1e-6f);
            dh1 = fminf(fmaxf(dh1, -1.0f), 1.0f);
            hnew[N + n] = h[N + n] + dh1;
        }
    }
}

// ---------------------------------------------------------------------------
// Fallback path (ws too small): atomic edge + update kernels.
// ---------------------------------------------------------------------------
__global__ __launch_bounds__(256) void edge_kernel(
    const int* __restrict__ eidx, const float* __restrict__ packed,
    float* __restrict__ flows, float* __restrict__ netT, int E)
{
    const int e = blockIdx.x * blockDim.x + threadIdx.x;
    if (e >= E) return;
    const int s = eidx[e];
    const int d = eidx[E + e];
    const float4 ps = *reinterpret_cast<const float4*>(&packed[4 * s]);
    const float4 pd = *reinterpret_cast<const float4*>(&packed[4 * d]);
    {
        const float dh = ps.x - pd.x;
        const float sg = (dh > 0.f) ? 1.f : ((dh < 0.f) ? -1.f : 0.f);
        float f = ps.z * sg * sqrtf(fabsf(dh) + 1e-6f);
        f = fminf(fmaxf(f, -10.0f), 10.0f);
        flows[e] = f;
        unsafeAtomicAdd(&netT[2 * d + 0],  f);
        unsafeAtomicAdd(&netT[2 * s + 0], -f);
    }
    {
        const float dh = ps.y - pd.y;
        const float sg = (dh > 0.f) ? 1.f : ((dh < 0.f) ? -1.f : 0.f);
        float f = ps.w * sg * sqrtf(fabsf(dh) + 1e-6f);
        f = fminf(fmaxf(f, -10.0f), 10.0f);
        flows[(size_t)E + e] = f;
        unsafeAtomicAdd(&netT[2 * d + 1],  f);
        unsafeAtomicAdd(&netT[2 * s + 1], -f);
    }
}

__global__ __launch_bounds__(256) void update_kernel(
    const float* __restrict__ h, const float* __restrict__ netT,
    const float* __restrict__ areas, float* __restrict__ hnew, int N)
{
    const int n = blockIdx.x * blockDim.x + threadIdx.x;
    if (n >= N) return;
    const float2 nv = *reinterpret_cast<const float2*>(&netT[2 * n]);
    float dh0 = 300.0f * nv.x / (areas[n] + 1e-6f);
    dh0 = fminf(fmaxf(dh0, -1.0f), 1.0f);
    hnew[n] = h[n] + dh0;
    float dh1 = 300.0f * nv.y / (areas[N + n] + 1e-6f);
    dh1 = fminf(fmaxf(dh1, -1.0f), 1.0f);
    hnew[N + n] = h[N + n] + dh1;
}

extern "C" void kernel_launch(void* const* d_in, const int* in_sizes, int n_in,
                              void* d_out, int out_size, void* d_ws, size_t ws_size,
                              hipStream_t stream)
{
    const float* h    = (const float*)d_in[0];
    const float* z    = (const float*)d_in[1];
    const int*   eidx = (const int*)  d_in[2];
    const float* rain = (const float*)d_in[4];
    const float* W1   = (const float*)d_in[5];
    const float* b1   = (const float*)d_in[6];
    const float* W2   = (const float*)d_in[7];
    const float* b2   = (const float*)d_in[8];
    const float* Wa   = (const float*)d_in[9];
    const float* ba   = (const float*)d_in[10];

    const int R = in_sizes[0];      // B*N
    const int E = in_sizes[3];
    const int N = R / 2;

    float* out_h     = (float*)d_out;
    float* out_flows = out_h + R;

    char* wsB = (char*)d_ws;
    size_t off = 0;
    auto take = [&](size_t bytes) -> char* {
        char* p = wsB + off;
        off = (off + bytes + 255) & ~(size_t)255;
        return p;
    };
    float*    packed   = (float*)   take((size_t)4 * N * 4);
    float*    areas    = (float*)   take((size_t)R * 4);
    float*    netT     = (float*)   take((size_t)2 * N * 4);
    float*    W1P      = (float*)   take(W1P_FLOATS * 4);
    unsigned* counters = (unsigned*)take(MAXBUK * 4);

    const int nbuk = (N + 255) >> 8;
    int cap = (int)(((size_t)2 * E / (nbuk > 0 ? nbuk : 1)) * 5 / 4 + 512);
    cap = (cap + 255) & ~255;
    unsigned* keysG = (unsigned*)take((size_t)nbuk * cap * 4);
    float2*   valsG = (float2*)  take((size_t)nbuk * cap * 8);
    const bool binned = (off <= ws_size) && (nbuk <= 256);

    const int packBlocks = max((N + 255) / 256, 16);
    pack_kernel<<<packBlocks, 256, 0, stream>>>(h, rain, W1, packed, netT,
                                                W1P, counters, N);
    // 4R threads: 16 lanes (2 kh x 8 s) per 4 rows -> ceil(R/64) blocks
    node_kernel<<<(R + 63) / 64, 256, 0, stream>>>(z, W1P, b1, W2, b2, Wa, ba,
                                                   packed, areas, N, R);
    if (binned) {
        edge_bin_kernel<<<(E + E1_EPB - 1) / E1_EPB, E1_TPB, 0, stream>>>(
            eidx, packed, out_flows, keysG, valsG, counters, E, nbuk, cap);
        bucket_reduce_kernel<<<nbuk, 512, 0, stream>>>(
            keysG, valsG, counters, h, rain, areas, out_h, N, cap);
    } else {
        edge_kernel<<<(E + 255) / 256, 256, 0, stream>>>(eidx, packed,
                                                         out_flows, netT, E);
        update_kernel<<<(N + 255) / 256, 256, 0, stream>>>(h, netT, areas,
                                                           out_h, N);
    }
}

// Round 10
// 170.284 us; speedup vs baseline: 1.0048x; 1.0048x over previous
//
#include <hip/hip_runtime.h>
#include <math.h>

#define HIDDEN 128
#define MAXBUK 512
#define E1_TPB 256
#define E1_EPT 4
#define E1_EPB (E1_TPB * E1_EPT)   // 1024 edges per block
#define E1_PPB (E1_EPB * 2)        // 2048 pairs per block

// W1P layout: [t 0..32)][kh 0..2)][s 0..8)][18]
//   idx = t*288 + kh*144 + s*18 + ii   (ii 0..15, 2 pad)
#define W1P_T_STRIDE  288
#define W1P_KH_STRIDE 144
#define W1P_S_STRIDE  18
#define W1P_FLOATS    (32 * W1P_T_STRIDE)   // 9216 floats = 36864 B

typedef float f32x4_t __attribute__((ext_vector_type(4)));

// Opaque (non-rematerializable) 16B global load: forces the value to live in
// VGPRs across the k-loop instead of being re-loaded (rounds 7-9: allocator
// remats plain loads, costing ~2x). Must be followed by vmcnt(0)+sched_barrier
// before first use.
__device__ __forceinline__ f32x4_t gload4(const float* p) {
    f32x4_t r;
    asm volatile("global_load_dwordx4 %0, %1, off"
                 : "=v"(r) : "v"(p) : "memory");
    return r;
}

// ---- DPP cross-lane helpers (ALL on VALU pipe; no DS ops in hot loop) ------
__device__ __forceinline__ float dpp_xor1(float v) {
    int t = __builtin_amdgcn_update_dpp(0, __float_as_int(v),
                                        0xB1, 0xF, 0xF, true); // quad_perm [1,0,3,2]
    return __int_as_float(t);
}
__device__ __forceinline__ float dpp_xor2(float v) {
    int t = __builtin_amdgcn_update_dpp(0, __float_as_int(v),
                                        0x4E, 0xF, 0xF, true); // quad_perm [2,3,0,1]
    return __int_as_float(t);
}
// lane^4 exchange+add: half_mirror (i^7) then quad_perm[3,2,1,0] (i^3) -> i^4
__device__ __forceinline__ float xor4_add(float v) {
    int t1 = __builtin_amdgcn_update_dpp(0, __float_as_int(v),
                                         0x141, 0xF, 0xF, true); // row_half_mirror
    int t2 = __builtin_amdgcn_update_dpp(0, t1,
                                         0x1B, 0xF, 0xF, true);  // quad_perm [3,2,1,0]
    return v + __int_as_float(t2);
}
// lane^8 exchange+add within 16-lane row: row_ror:8
__device__ __forceinline__ float xor8_add(float v) {
    int t = __builtin_amdgcn_update_dpp(0, __float_as_int(v),
                                        0x128, 0xF, 0xF, true);  // row_ror:8
    return v + __int_as_float(t);
}

// fast gelu: 0.5x(1+erf(x/sqrt2)), A&S 7.1.26, |erf err|<=2e-7
__device__ __forceinline__ float gelu_fast(float x) {
    const float u  = x * 0.70710678118654752f;
    const float au = fabsf(u);
    const float t  = __builtin_amdgcn_rcpf(fmaf(0.3275911f, au, 1.0f));
    float poly = fmaf(1.061405429f, t, -1.453152027f);
    poly = fmaf(poly, t, 1.421413741f);
    poly = fmaf(poly, t, -0.284496736f);
    poly = fmaf(poly, t, 0.254829592f);
    poly *= t;
    const float e = __expf(-au * au);
    const float erfabs = fmaf(-poly, e, 1.0f);
    const float erfv = copysignf(erfabs, u);
    return 0.5f * x * (1.0f + erfv);
}

// ---------------------------------------------------------------------------
// Pack + prep fused.
// ---------------------------------------------------------------------------
__global__ __launch_bounds__(256) void pack_kernel(
    const float* __restrict__ h, const float* __restrict__ rain,
    const float* __restrict__ W1,
    float* __restrict__ packed, float* __restrict__ netT,
    float* __restrict__ W1P, unsigned* __restrict__ counters, int N)
{
    const int tid = threadIdx.x;
    const int b = blockIdx.x;
    if (b < 16) {
        for (int i = tid; i < 512; i += 256) {
            const int k  = 4 * b + (i >> 7);     // 0..63
            const int hh = i & 127;
            const int s  = hh >> 4, ii = hh & 15;
            const int kh = k >> 5, t = k & 31;
            W1P[t * W1P_T_STRIDE + kh * W1P_KH_STRIDE + s * W1P_S_STRIDE + ii]
                = W1[hh * 64 + k];
        }
        if (b == 0)
            for (int i = tid; i < MAXBUK; i += 256) counters[i] = 0u;
    }
    const int n = b * blockDim.x + tid;
    if (n >= N) return;
    *reinterpret_cast<float2*>(&packed[4 * n]) = make_float2(h[n], h[N + n]);
    *reinterpret_cast<float2*>(&netT[2 * n])   = make_float2(rain[n], rain[N + n]);
}

// ---------------------------------------------------------------------------
// Node kernel v10: 16-lane groups = (kh 2) x (s 8) own 4 rows.
//  z slices pinned in VGPRs via opaque asm loads (no remat possible).
//  All reductions DPP/VALU; W ds_reads pipeline freely (no lgkm drain).
// ---------------------------------------------------------------------------
__global__ __launch_bounds__(256) void node_kernel(
    const float* __restrict__ z,     // [R][128]
    const float* __restrict__ W1P,   // [32][2][8][18]
    const float* __restrict__ b1, const float* __restrict__ W2,
    const float* __restrict__ b2, const float* __restrict__ Wa,
    const float* __restrict__ ba,
    float* __restrict__ packed, float* __restrict__ areas,
    int N, int R)
{
    __shared__ float w1s[W1P_FLOATS];   // 36864 B
    __shared__ float bw[128];           // interleaved (b1[k], W2[k])
    __shared__ float was[128];

    const int tid = threadIdx.x;
    for (int i = tid; i < W1P_FLOATS; i += 256) w1s[i] = W1P[i];
    if (tid < 64)       { bw[2 * tid] = b1[tid]; bw[2 * tid + 1] = W2[tid]; }
    else if (tid < 192) was[tid - 64] = Wa[tid - 64];
    __syncthreads();

    const int s  = tid & 7;            // h-slice (16 floats)
    const int kh = (tid >> 3) & 1;     // k-half (32 of 64 cols)
    const int r0 = ((blockIdx.x * 256 + tid) >> 4) * 4;  // group's 4 rows
    if (r0 >= R) return;               // R % 4 == 0, group-uniform

    // 4 rows x 16-float slice -> 16 asm-pinned float4s (64 VGPRs)
    f32x4_t zq[4][4];
#pragma unroll
    for (int j = 0; j < 4; ++j) {
        const float* zp = z + (size_t)(r0 + j) * HIDDEN + s * 16;
#pragma unroll
        for (int i = 0; i < 4; ++i)
            zq[j][i] = gload4(zp + 4 * i);
    }
    asm volatile("s_waitcnt vmcnt(0)" ::: "memory");
    __builtin_amdgcn_sched_barrier(0);

    const bool e1 = (s & 1) == 0;
    const bool e2 = (s & 2) == 0;

    float cf = 0.f;                     // row (s&3), this k-half
    const float* __restrict__ wbase =
        &w1s[kh * W1P_KH_STRIDE + s * W1P_S_STRIDE];
    const float* __restrict__ bwbase = &bw[kh * 64];

#pragma unroll 2
    for (int t = 0; t < 32; ++t) {
        const float* __restrict__ wk = wbase + t * W1P_T_STRIDE;
        float p0 = 0.f, p1 = 0.f, p2 = 0.f, p3 = 0.f;
#pragma unroll
        for (int i = 0; i < 4; ++i) {
            const float4 w = *reinterpret_cast<const float4*>(&wk[4 * i]);
            p0 = fmaf(zq[0][i].x, w.x, p0);
            p1 = fmaf(zq[1][i].x, w.x, p1);
            p2 = fmaf(zq[2][i].x, w.x, p2);
            p3 = fmaf(zq[3][i].x, w.x, p3);
            p0 = fmaf(zq[0][i].y, w.y, p0);
            p1 = fmaf(zq[1][i].y, w.y, p1);
            p2 = fmaf(zq[2][i].y, w.y, p2);
            p3 = fmaf(zq[3][i].y, w.y, p3);
            p0 = fmaf(zq[0][i].z, w.z, p0);
            p1 = fmaf(zq[1][i].z, w.z, p1);
            p2 = fmaf(zq[2][i].z, w.z, p2);
            p3 = fmaf(zq[3][i].z, w.z, p3);
            p0 = fmaf(zq[0][i].w, w.w, p0);
            p1 = fmaf(zq[1][i].w, w.w, p1);
            p2 = fmaf(zq[2][i].w, w.w, p2);
            p3 = fmaf(zq[3][i].w, w.w, p3);
        }
        // quad transpose-reduce: lane ends with row (s&3) over its slice-quad
        const float a   = e1 ? p0 : p1, b = e1 ? p1 : p0;
        const float ulo = a + dpp_xor1(b);
        const float c   = e1 ? p2 : p3, d = e1 ? p3 : p2;
        const float uhi = c + dpp_xor1(d);
        const float a2  = e2 ? ulo : uhi, b2v = e2 ? uhi : ulo;
        const float x4  = a2 + dpp_xor2(b2v);
        const float x8  = xor4_add(x4);             // join slice-quads (DPP)

        const float2 bwk = *reinterpret_cast<const float2*>(&bwbase[2 * t]);
        const float g = gelu_fast(x8 + bwk.x);
        cf = fmaf(g, bwk.y, cf);                    // one gelu+fma per lane
    }
    const float cf_full = xor8_add(cf);             // combine k-halves (DPP)

    // areas: 16-float slice dot, same reduction (kh-redundant)
    float q0 = 0.f, q1 = 0.f, q2 = 0.f, q3 = 0.f;
#pragma unroll
    for (int i = 0; i < 4; ++i) {
        const float4 wv = *reinterpret_cast<const float4*>(&was[s * 16 + 4 * i]);
        q0 = fmaf(zq[0][i].x, wv.x, q0);
        q1 = fmaf(zq[1][i].x, wv.x, q1);
        q2 = fmaf(zq[2][i].x, wv.x, q2);
        q3 = fmaf(zq[3][i].x, wv.x, q3);
        q0 = fmaf(zq[0][i].y, wv.y, q0);
        q1 = fmaf(zq[1][i].y, wv.y, q1);
        q2 = fmaf(zq[2][i].y, wv.y, q2);
        q3 = fmaf(zq[3][i].y, wv.y, q3);
        q0 = fmaf(zq[0][i].z, wv.z, q0);
        q1 = fmaf(zq[1][i].z, wv.z, q1);
        q2 = fmaf(zq[2][i].z, wv.z, q2);
        q3 = fmaf(zq[3][i].z, wv.z, q3);
        q0 = fmaf(zq[0][i].w, wv.w, q0);
        q1 = fmaf(zq[1][i].w, wv.w, q1);
        q2 = fmaf(zq[2][i].w, wv.w, q2);
        q3 = fmaf(zq[3][i].w, wv.w, q3);
    }
    const float aa  = e1 ? q0 : q1, ab = e1 ? q1 : q0;
    const float alo = aa + dpp_xor1(ab);
    const float ac  = e1 ? q2 : q3, adt = e1 ? q3 : q2;
    const float ahi = ac + dpp_xor1(adt);
    const float aa2 = e2 ? alo : ahi, ab2 = e2 ? ahi : alo;
    const float a4  = aa2 + dpp_xor2(ab2);
    const float ad  = xor4_add(a4);                 // row (s&3) z@Wa (DPP)

    if ((tid & 12) == 0) {                          // kh==0 && s<4
        const int r = r0 + (s & 3);
        const float cv   = 1.0f / (1.0f + expf(-(cf_full + b2[0])));
        const float adv  = ad + ba[0];
        const float area = fmaxf(adv, 0.f) + log1pf(expf(-fabsf(adv)));
        const int bb = (r >= N) ? 1 : 0;
        const int n = r - bb * N;
        packed[4 * n + 2 + bb] = cv;
        areas[r] = area;
    }
}

// ---------------------------------------------------------------------------
// E1: per-edge flows + in-block counting-sort of (node, +/-f0,f1) pairs into
// per-bucket global segments (bucket = node>>8). ~196 int atomics per block.
// ---------------------------------------------------------------------------
__global__ __launch_bounds__(E1_TPB) void edge_bin_kernel(
    const int* __restrict__ eidx,      // [2][E]
    const float* __restrict__ packed,  // [N][4] = h0,h1,c0,c1
    float* __restrict__ flows,         // [2][E]
    unsigned* __restrict__ keysG,      // [nbuk][cap]
    float2* __restrict__ valsG,        // [nbuk][cap]
    unsigned* __restrict__ counters,   // [nbuk]
    int E, int nbuk, int cap)
{
    __shared__ unsigned hist[MAXBUK];
    __shared__ unsigned base[MAXBUK];
    __shared__ unsigned gbase[MAXBUK];
    __shared__ unsigned scan[E1_TPB];
    __shared__ unsigned skey[E1_PPB];
    __shared__ float2   sval[E1_PPB];

    const int tid = threadIdx.x;
    const int e0  = blockIdx.x * E1_EPB;

    for (int i = tid; i < nbuk; i += E1_TPB) hist[i] = 0;
    __syncthreads();

    unsigned mykey[2 * E1_EPT];
    unsigned myoff[2 * E1_EPT];
    float2   myval[2 * E1_EPT];

#pragma unroll
    for (int j = 0; j < E1_EPT; ++j) {
        const int e = e0 + j * E1_TPB + tid;
        unsigned kd = 0xFFFFFFFFu, ks = 0xFFFFFFFFu;
        float2 vd = make_float2(0.f, 0.f), vs = vd;
        if (e < E) {
            const int s = eidx[e];
            const int d = eidx[E + e];
            const float4 ps = *reinterpret_cast<const float4*>(&packed[4 * s]);
            const float4 pd = *reinterpret_cast<const float4*>(&packed[4 * d]);

            float dh = ps.x - pd.x;
            float sg = (dh > 0.f) ? 1.f : ((dh < 0.f) ? -1.f : 0.f);
            float f0 = ps.z * sg * sqrtf(fabsf(dh) + 1e-6f);
            f0 = fminf(fmaxf(f0, -10.0f), 10.0f);

            dh = ps.y - pd.y;
            sg = (dh > 0.f) ? 1.f : ((dh < 0.f) ? -1.f : 0.f);
            float f1 = ps.w * sg * sqrtf(fabsf(dh) + 1e-6f);
            f1 = fminf(fmaxf(f1, -10.0f), 10.0f);

            flows[e] = f0;
            flows[(size_t)E + e] = f1;

            kd = (unsigned)d; vd = make_float2(f0, f1);
            ks = (unsigned)s; vs = make_float2(-f0, -f1);
        }
        mykey[2 * j]     = kd; myval[2 * j]     = vd;
        mykey[2 * j + 1] = ks; myval[2 * j + 1] = vs;
        if (kd != 0xFFFFFFFFu) {
            myoff[2 * j]     = atomicAdd(&hist[kd >> 8], 1u);
            myoff[2 * j + 1] = atomicAdd(&hist[ks >> 8], 1u);
        }
    }
    __syncthreads();

    // Hillis-Steele inclusive scan of hist (nbuk <= 256)
    const unsigned hv = (tid < nbuk) ? hist[tid] : 0u;
    scan[tid] = hv;
    __syncthreads();
    for (int off = 1; off < E1_TPB; off <<= 1) {
        unsigned t = (tid >= off) ? scan[tid - off] : 0u;
        __syncthreads();
        scan[tid] += t;
        __syncthreads();
    }
    if (tid < nbuk) {
        base[tid] = scan[tid] - hv;
        if (hv > 0) gbase[tid] = atomicAdd(&counters[tid], hv);
    }
    __syncthreads();

#pragma unroll
    for (int j = 0; j < 2 * E1_EPT; ++j) {
        const unsigned k = mykey[j];
        if (k != 0xFFFFFFFFu) {
            const unsigned idx = base[k >> 8] + myoff[j];
            skey[idx] = k;
            sval[idx] = myval[j];
        }
    }
    __syncthreads();

    const int tot = 2 * min(E1_EPB, E - e0);
    for (int i = tid; i < tot; i += E1_TPB) {
        const unsigned k = skey[i];
        const unsigned bb = k >> 8;
        const unsigned pos = gbase[bb] + ((unsigned)i - base[bb]);
        if (pos < (unsigned)cap) {
            keysG[(size_t)bb * cap + pos] = k;
            valsG[(size_t)bb * cap + pos] = sval[i];
        }
    }
}

// ---------------------------------------------------------------------------
// E2: one block (512 thr) per bucket; FOUR LDS accumulator copies cut
// same-node atomic serialization. Fused h-update. No global f32 atomics.
// ---------------------------------------------------------------------------
__global__ __launch_bounds__(512) void bucket_reduce_kernel(
    const unsigned* __restrict__ keysG, const float2* __restrict__ valsG,
    const unsigned* __restrict__ counters,
    const float* __restrict__ h, const float* __restrict__ rain,
    const float* __restrict__ areas,
    float* __restrict__ hnew, int N, int cap)
{
    __shared__ float accx[4][256], accy[4][256];   // 8 KB
    const int tid = threadIdx.x;
    const int b = blockIdx.x;
    const int q = tid >> 7;                        // 4 groups of 128
    {
        float* fx = &accx[0][0];
        float* fy = &accy[0][0];
        fx[tid] = 0.f; fx[tid + 512] = 0.f;
        fy[tid] = 0.f; fy[tid + 512] = 0.f;
    }
    __syncthreads();

    const int cnt = min((int)counters[b], cap);
    const unsigned* __restrict__ sk = keysG + (size_t)b * cap;
    const float2*  __restrict__  sv = valsG + (size_t)b * cap;
    for (int i = tid; i < cnt; i += 512) {
        const unsigned k = sk[i];
        const float2 v2 = sv[i];
        const int loc = (int)(k & 255u);
        atomicAdd(&accx[q][loc], v2.x);
        atomicAdd(&accy[q][loc], v2.y);
    }
    __syncthreads();

    if (tid < 256) {
        const int n = (b << 8) + tid;
        if (n < N) {
            const float net0 = rain[n]     + ((accx[0][tid] + accx[1][tid])
                                           + (accx[2][tid] + accx[3][tid]));
            const float net1 = rain[N + n] + ((accy[0][tid] + accy[1][tid])
                                           + (accy[2][tid] + accy[3][tid]));
            float dh0 = 300.0f * net0 / (areas[n] + 1e-6f);
            dh0 = fminf(fmaxf(dh0, -1.0f), 1.0f);
            hnew[n] = h[n] + dh0;
            float dh1 = 300.0f * net1 / (areas[N + n] + 1e-6f);
            dh1 = fminf(fmaxf(dh1, -1.0f), 1.0f);
            hnew[N + n] = h[N + n] + dh1;
        }
    }
}

// ---------------------------------------------------------------------------
// Fallback path (ws too small): atomic edge + update kernels.
// ---------------------------------------------------------------------------
__global__ __launch_bounds__(256) void edge_kernel(
    const int* __restrict__ eidx, const float* __restrict__ packed,
    float* __restrict__ flows, float* __restrict__ netT, int E)
{
    const int e = blockIdx.x * blockDim.x + threadIdx.x;
    if (e >= E) return;
    const int s = eidx[e];
    const int d = eidx[E + e];
    const float4 ps = *reinterpret_cast<const float4*>(&packed[4 * s]);
    const float4 pd = *reinterpret_cast<const float4*>(&packed[4 * d]);
    {
        const float dh = ps.x - pd.x;
        const float sg = (dh > 0.f) ? 1.f : ((dh < 0.f) ? -1.f : 0.f);
        float f = ps.z * sg * sqrtf(fabsf(dh) + 1e-6f);
        f = fminf(fmaxf(f, -10.0f), 10.0f);
        flows[e] = f;
        unsafeAtomicAdd(&netT[2 * d + 0],  f);
        unsafeAtomicAdd(&netT[2 * s + 0], -f);
    }
    {
        const float dh = ps.y - pd.y;
        const float sg = (dh > 0.f) ? 1.f : ((dh < 0.f) ? -1.f : 0.f);
        float f = ps.w * sg * sqrtf(fabsf(dh) + 1e-6f);
        f = fminf(fmaxf(f, -10.0f), 10.0f);
        flows[(size_t)E + e] = f;
        unsafeAtomicAdd(&netT[2 * d + 1],  f);
        unsafeAtomicAdd(&netT[2 * s + 1], -f);
    }
}

__global__ __launch_bounds__(256) void update_kernel(
    const float* __restrict__ h, const float* __restrict__ netT,
    const float* __restrict__ areas, float* __restrict__ hnew, int N)
{
    const int n = blockIdx.x * blockDim.x + threadIdx.x;
    if (n >= N) return;
    const float2 nv = *reinterpret_cast<const float2*>(&netT[2 * n]);
    float dh0 = 300.0f * nv.x / (areas[n] + 1e-6f);
    dh0 = fminf(fmaxf(dh0, -1.0f), 1.0f);
    hnew[n] = h[n] + dh0;
    float dh1 = 300.0f * nv.y / (areas[N + n] + 1e-6f);
    dh1 = fminf(fmaxf(dh1, -1.0f), 1.0f);
    hnew[N + n] = h[N + n] + dh1;
}

extern "C" void kernel_launch(void* const* d_in, const int* in_sizes, int n_in,
                              void* d_out, int out_size, void* d_ws, size_t ws_size,
                              hipStream_t stream)
{
    const float* h    = (const float*)d_in[0];
    const float* z    = (const float*)d_in[1];
    const int*   eidx = (const int*)  d_in[2];
    const float* rain = (const float*)d_in[4];
    const float* W1   = (const float*)d_in[5];
    const float* b1   = (const float*)d_in[6];
    const float* W2   = (const float*)d_in[7];
    const float* b2   = (const float*)d_in[8];
    const float* Wa   = (const float*)d_in[9];
    const float* ba   = (const float*)d_in[10];

    const int R = in_sizes[0];      // B*N
    const int E = in_sizes[3];
    const int N = R / 2;

    float* out_h     = (float*)d_out;
    float* out_flows = out_h + R;

    char* wsB = (char*)d_ws;
    size_t off = 0;
    auto take = [&](size_t bytes) -> char* {
        char* p = wsB + off;
        off = (off + bytes + 255) & ~(size_t)255;
        return p;
    };
    float*    packed   = (float*)   take((size_t)4 * N * 4);
    float*    areas    = (float*)   take((size_t)R * 4);
    float*    netT     = (float*)   take((size_t)2 * N * 4);
    float*    W1P      = (float*)   take(W1P_FLOATS * 4);
    unsigned* counters = (unsigned*)take(MAXBUK * 4);

    const int nbuk = (N + 255) >> 8;
    int cap = (int)(((size_t)2 * E / (nbuk > 0 ? nbuk : 1)) * 5 / 4 + 512);
    cap = (cap + 255) & ~255;
    unsigned* keysG = (unsigned*)take((size_t)nbuk * cap * 4);
    float2*   valsG = (float2*)  take((size_t)nbuk * cap * 8);
    const bool binned = (off <= ws_size) && (nbuk <= 256);

    const int packBlocks = max((N + 255) / 256, 16);
    pack_kernel<<<packBlocks, 256, 0, stream>>>(h, rain, W1, packed, netT,
                                                W1P, counters, N);
    // 4R threads: 16 lanes (2 kh x 8 s) per 4 rows -> ceil(R/64) blocks
    node_kernel<<<(R + 63) / 64, 256, 0, stream>>>(z, W1P, b1, W2, b2, Wa, ba,
                                                   packed, areas, N, R);
    if (binned) {
        edge_bin_kernel<<<(E + E1_EPB - 1) / E1_EPB, E1_TPB, 0, stream>>>(
            eidx, packed, out_flows, keysG, valsG, counters, E, nbuk, cap);
        bucket_reduce_kernel<<<nbuk, 512, 0, stream>>>(
            keysG, valsG, counters, h, rain, areas, out_h, N, cap);
    } else {
        edge_kernel<<<(E + 255) / 256, 256, 0, stream>>>(eidx, packed,
                                                         out_flows, netT, E);
        update_kernel<<<(N + 255) / 256, 256, 0, stream>>>(h, netT, areas,
                                                           out_h, N);
    }
}

// Round 11
// 107.353 us; speedup vs baseline: 1.5938x; 1.5862x over previous
//
#include <hip/hip_runtime.h>
#include <math.h>

#define HIDDEN 128
#define MAXBUK 512
#define E1_TPB 256
#define E1_EPT 4
#define E1_EPB (E1_TPB * E1_EPT)   // 1024 edges per block
#define E1_PPB (E1_EPB * 2)        // 2048 pairs per block

// W1 LDS layout: [h 0..128)][68]  (64 cols used + 4 pad)
#define W1S_H_STRIDE 68

// pair-lane exchange+add via DPP quad_perm [1,0,3,2] (VALU pipe)
__device__ __forceinline__ float dpp_xor1(float v) {
    int t = __builtin_amdgcn_update_dpp(0, __float_as_int(v),
                                        0xB1, 0xF, 0xF, true);
    return __int_as_float(t);
}

// fast gelu: 0.5x(1+erf(x/sqrt2)), A&S 7.1.26, |erf err|<=2e-7
__device__ __forceinline__ float gelu_fast(float x) {
    const float u  = x * 0.70710678118654752f;
    const float au = fabsf(u);
    const float t  = __builtin_amdgcn_rcpf(fmaf(0.3275911f, au, 1.0f));
    float poly = fmaf(1.061405429f, t, -1.453152027f);
    poly = fmaf(poly, t, 1.421413741f);
    poly = fmaf(poly, t, -0.284496736f);
    poly = fmaf(poly, t, 0.254829592f);
    poly *= t;
    const float e = __expf(-au * au);
    const float erfabs = fmaf(-poly, e, 1.0f);
    const float erfv = copysignf(erfabs, u);
    return 0.5f * x * (1.0f + erfv);
}

// ---------------------------------------------------------------------------
// Pack: packed[n] = (h0,h1,<c0>,<c1>); netT[n] = (rain0,rain1);
// block 0 zeros the bucket counters.
// ---------------------------------------------------------------------------
__global__ __launch_bounds__(256) void pack_kernel(
    const float* __restrict__ h, const float* __restrict__ rain,
    float* __restrict__ packed, float* __restrict__ netT,
    unsigned* __restrict__ counters, int N)
{
    const int tid = threadIdx.x;
    const int b = blockIdx.x;
    if (b == 0)
        for (int i = tid; i < MAXBUK; i += 256) counters[i] = 0u;
    const int n = b * blockDim.x + tid;
    if (n >= N) return;
    *reinterpret_cast<float2*>(&packed[4 * n]) = make_float2(h[n], h[N + n]);
    *reinterpret_cast<float2*>(&netT[2 * n])   = make_float2(rain[n], rain[N + n]);
}

// ---------------------------------------------------------------------------
// Node kernel v11: LANE-PAIR per row; parity owns a k-half (32 cols).
//  - acc[32] per lane: accumulators are non-rematerializable -> stay in VGPRs
//  - z streamed as float4, used immediately (no long-lived array to remat);
//    both pair lanes read the SAME address -> one fetch (broadcast coalesce)
//  - W1 in LDS, reads wave-uniform per parity (2 addrs -> broadcast, no
//    bank conflicts)
//  - 32 gelus per lane, zero redundancy; k-halves joined by one dpp_xor1
// ---------------------------------------------------------------------------
__global__ __launch_bounds__(256) void node_kernel(
    const float* __restrict__ z,     // [R][128]
    const float* __restrict__ W1,    // [128][64] row-major
    const float* __restrict__ b1, const float* __restrict__ W2,
    const float* __restrict__ b2, const float* __restrict__ Wa,
    const float* __restrict__ ba,
    float* __restrict__ packed, float* __restrict__ areas,
    int N, int R)
{
    __shared__ float w1s[128 * W1S_H_STRIDE];   // 34816 B
    __shared__ float b1s[64], w2s[64], was[128];

    const int tid = threadIdx.x;
    for (int i = tid; i < 128 * 64; i += 256) {
        const int hh = i >> 6, k = i & 63;
        w1s[hh * W1S_H_STRIDE + k] = W1[i];
    }
    if (tid < 64)       b1s[tid] = b1[tid];
    else if (tid < 128) w2s[tid - 64] = W2[tid - 64];
    else                was[tid - 128] = Wa[tid - 128];
    __syncthreads();

    const int p   = tid & 1;                       // k-half (parity)
    const int row = (blockIdx.x * 256 + tid) >> 1; // lane pair -> one row
    if (row >= R) return;

    float acc[32];
#pragma unroll
    for (int k = 0; k < 32; ++k) acc[k] = 0.f;
    float ad = 0.f;

    const float* __restrict__ zrow = z + (size_t)row * HIDDEN;
    const float* __restrict__ wbase = &w1s[p * 32];

#pragma unroll 4
    for (int i = 0; i < 32; ++i) {
        const float4 zv = *reinterpret_cast<const float4*>(zrow + 4 * i);
#pragma unroll
        for (int j = 0; j < 4; ++j) {
            const float zj = (j == 0) ? zv.x : (j == 1) ? zv.y
                           : (j == 2) ? zv.z : zv.w;
            const float* __restrict__ wj =
                wbase + (4 * i + j) * W1S_H_STRIDE;
#pragma unroll
            for (int kq = 0; kq < 8; ++kq) {
                const float4 w = *reinterpret_cast<const float4*>(wj + 4 * kq);
                acc[4 * kq + 0] = fmaf(zj, w.x, acc[4 * kq + 0]);
                acc[4 * kq + 1] = fmaf(zj, w.y, acc[4 * kq + 1]);
                acc[4 * kq + 2] = fmaf(zj, w.z, acc[4 * kq + 2]);
                acc[4 * kq + 3] = fmaf(zj, w.w, acc[4 * kq + 3]);
            }
        }
        const float4 wa = *reinterpret_cast<const float4*>(&was[4 * i]);
        ad = fmaf(zv.x, wa.x, ad);
        ad = fmaf(zv.y, wa.y, ad);
        ad = fmaf(zv.z, wa.z, ad);
        ad = fmaf(zv.w, wa.w, ad);
    }

    // epilogue: gelu + W2 dot over this lane's 32 k's
    float cf = 0.f;
#pragma unroll
    for (int kk = 0; kk < 32; ++kk) {
        const float x = acc[kk] + b1s[p * 32 + kk];
        cf = fmaf(gelu_fast(x), w2s[p * 32 + kk], cf);
    }
    const float cf_full = cf + dpp_xor1(cf);       // join k-halves (pair)

    if (p == 0) {
        const float cv   = 1.0f / (1.0f + expf(-(cf_full + b2[0])));
        const float adv  = ad + ba[0];
        const float area = fmaxf(adv, 0.f) + log1pf(expf(-fabsf(adv)));
        const int bb = (row >= N) ? 1 : 0;
        const int n = row - bb * N;
        packed[4 * n + 2 + bb] = cv;
        areas[row] = area;
    }
}

// ---------------------------------------------------------------------------
// E1: per-edge flows + in-block counting-sort of (node, +/-f0,f1) pairs into
// per-bucket global segments (bucket = node>>8). ~196 int atomics per block.
// ---------------------------------------------------------------------------
__global__ __launch_bounds__(E1_TPB) void edge_bin_kernel(
    const int* __restrict__ eidx,      // [2][E]
    const float* __restrict__ packed,  // [N][4] = h0,h1,c0,c1
    float* __restrict__ flows,         // [2][E]
    unsigned* __restrict__ keysG,      // [nbuk][cap]
    float2* __restrict__ valsG,        // [nbuk][cap]
    unsigned* __restrict__ counters,   // [nbuk]
    int E, int nbuk, int cap)
{
    __shared__ unsigned hist[MAXBUK];
    __shared__ unsigned base[MAXBUK];
    __shared__ unsigned gbase[MAXBUK];
    __shared__ unsigned scan[E1_TPB];
    __shared__ unsigned skey[E1_PPB];
    __shared__ float2   sval[E1_PPB];

    const int tid = threadIdx.x;
    const int e0  = blockIdx.x * E1_EPB;

    for (int i = tid; i < nbuk; i += E1_TPB) hist[i] = 0;
    __syncthreads();

    unsigned mykey[2 * E1_EPT];
    unsigned myoff[2 * E1_EPT];
    float2   myval[2 * E1_EPT];

#pragma unroll
    for (int j = 0; j < E1_EPT; ++j) {
        const int e = e0 + j * E1_TPB + tid;
        unsigned kd = 0xFFFFFFFFu, ks = 0xFFFFFFFFu;
        float2 vd = make_float2(0.f, 0.f), vs = vd;
        if (e < E) {
            const int s = eidx[e];
            const int d = eidx[E + e];
            const float4 ps = *reinterpret_cast<const float4*>(&packed[4 * s]);
            const float4 pd = *reinterpret_cast<const float4*>(&packed[4 * d]);

            float dh = ps.x - pd.x;
            float sg = (dh > 0.f) ? 1.f : ((dh < 0.f) ? -1.f : 0.f);
            float f0 = ps.z * sg * sqrtf(fabsf(dh) + 1e-6f);
            f0 = fminf(fmaxf(f0, -10.0f), 10.0f);

            dh = ps.y - pd.y;
            sg = (dh > 0.f) ? 1.f : ((dh < 0.f) ? -1.f : 0.f);
            float f1 = ps.w * sg * sqrtf(fabsf(dh) + 1e-6f);
            f1 = fminf(fmaxf(f1, -10.0f), 10.0f);

            flows[e] = f0;
            flows[(size_t)E + e] = f1;

            kd = (unsigned)d; vd = make_float2(f0, f1);
            ks = (unsigned)s; vs = make_float2(-f0, -f1);
        }
        mykey[2 * j]     = kd; myval[2 * j]     = vd;
        mykey[2 * j + 1] = ks; myval[2 * j + 1] = vs;
        if (kd != 0xFFFFFFFFu) {
            myoff[2 * j]     = atomicAdd(&hist[kd >> 8], 1u);
            myoff[2 * j + 1] = atomicAdd(&hist[ks >> 8], 1u);
        }
    }
    __syncthreads();

    // Hillis-Steele inclusive scan of hist (nbuk <= 256)
    const unsigned hv = (tid < nbuk) ? hist[tid] : 0u;
    scan[tid] = hv;
    __syncthreads();
    for (int off = 1; off < E1_TPB; off <<= 1) {
        unsigned t = (tid >= off) ? scan[tid - off] : 0u;
        __syncthreads();
        scan[tid] += t;
        __syncthreads();
    }
    if (tid < nbuk) {
        base[tid] = scan[tid] - hv;
        if (hv > 0) gbase[tid] = atomicAdd(&counters[tid], hv);
    }
    __syncthreads();

#pragma unroll
    for (int j = 0; j < 2 * E1_EPT; ++j) {
        const unsigned k = mykey[j];
        if (k != 0xFFFFFFFFu) {
            const unsigned idx = base[k >> 8] + myoff[j];
            skey[idx] = k;
            sval[idx] = myval[j];
        }
    }
    __syncthreads();

    const int tot = 2 * min(E1_EPB, E - e0);
    for (int i = tid; i < tot; i += E1_TPB) {
        const unsigned k = skey[i];
        const unsigned bb = k >> 8;
        const unsigned pos = gbase[bb] + ((unsigned)i - base[bb]);
        if (pos < (unsigned)cap) {
            keysG[(size_t)bb * cap + pos] = k;
            valsG[(size_t)bb * cap + pos] = sval[i];
        }
    }
}

// ---------------------------------------------------------------------------
// E2: one block (512 thr) per bucket; FOUR LDS accumulator copies cut
// same-node atomic serialization. Fused h-update. No global f32 atomics.
// ---------------------------------------------------------------------------
__global__ __launch_bounds__(512) void bucket_reduce_kernel(
    const unsigned* __restrict__ keysG, const float2* __restrict__ valsG,
    const unsigned* __restrict__ counters,
    const float* __restrict__ h, const float* __restrict__ rain,
    const float* __restrict__ areas,
    float* __restrict__ hnew, int N, int cap)
{
    __shared__ float accx[4][256], accy[4][256];   // 8 KB
    const int tid = threadIdx.x;
    const int b = blockIdx.x;
    const int q = tid >> 7;                        // 4 groups of 128
    {
        float* fx = &accx[0][0];
        float* fy = &accy[0][0];
        fx[tid] = 0.f; fx[tid + 512] = 0.f;
        fy[tid] = 0.f; fy[tid + 512] = 0.f;
    }
    __syncthreads();

    const int cnt = min((int)counters[b], cap);
    const unsigned* __restrict__ sk = keysG + (size_t)b * cap;
    const float2*  __restrict__  sv = valsG + (size_t)b * cap;
    for (int i = tid; i < cnt; i += 512) {
        const unsigned k = sk[i];
        const float2 v2 = sv[i];
        const int loc = (int)(k & 255u);
        atomicAdd(&accx[q][loc], v2.x);
        atomicAdd(&accy[q][loc], v2.y);
    }
    __syncthreads();

    if (tid < 256) {
        const int n = (b << 8) + tid;
        if (n < N) {
            const float net0 = rain[n]     + ((accx[0][tid] + accx[1][tid])
                                           + (accx[2][tid] + accx[3][tid]));
            const float net1 = rain[N + n] + ((accy[0][tid] + accy[1][tid])
                                           + (accy[2][tid] + accy[3][tid]));
            float dh0 = 300.0f * net0 / (areas[n] + 1e-6f);
            dh0 = fminf(fmaxf(dh0, -1.0f), 1.0f);
            hnew[n] = h[n] + dh0;
            float dh1 = 300.0f * net1 / (areas[N + n] + 1e-6f);
            dh1 = fminf(fmaxf(dh1, -1.0f), 1.0f);
            hnew[N + n] = h[N + n] + dh1;
        }
    }
}

// ---------------------------------------------------------------------------
// Fallback path (ws too small): atomic edge + update kernels.
// ---------------------------------------------------------------------------
__global__ __launch_bounds__(256) void edge_kernel(
    const int* __restrict__ eidx, const float* __restrict__ packed,
    float* __restrict__ flows, float* __restrict__ netT, int E)
{
    const int e = blockIdx.x * blockDim.x + threadIdx.x;
    if (e >= E) return;
    const int s = eidx[e];
    const int d = eidx[E + e];
    const float4 ps = *reinterpret_cast<const float4*>(&packed[4 * s]);
    const float4 pd = *reinterpret_cast<const float4*>(&packed[4 * d]);
    {
        const float dh = ps.x - pd.x;
        const float sg = (dh > 0.f) ? 1.f : ((dh < 0.f) ? -1.f : 0.f);
        float f = ps.z * sg * sqrtf(fabsf(dh) + 1e-6f);
        f = fminf(fmaxf(f, -10.0f), 10.0f);
        flows[e] = f;
        unsafeAtomicAdd(&netT[2 * d + 0],  f);
        unsafeAtomicAdd(&netT[2 * s + 0], -f);
    }
    {
        const float dh = ps.y - pd.y;
        const float sg = (dh > 0.f) ? 1.f : ((dh < 0.f) ? -1.f : 0.f);
        float f = ps.w * sg * sqrtf(fabsf(dh) + 1e-6f);
        f = fminf(fmaxf(f, -10.0f), 10.0f);
        flows[(size_t)E + e] = f;
        unsafeAtomicAdd(&netT[2 * d + 1],  f);
        unsafeAtomicAdd(&netT[2 * s + 1], -f);
    }
}

__global__ __launch_bounds__(256) void update_kernel(
    const float* __restrict__ h, const float* __restrict__ netT,
    const float* __restrict__ areas, float* __restrict__ hnew, int N)
{
    const int n = blockIdx.x * blockDim.x + threadIdx.x;
    if (n >= N) return;
    const float2 nv = *reinterpret_cast<const float2*>(&netT[2 * n]);
    float dh0 = 300.0f * nv.x / (areas[n] + 1e-6f);
    dh0 = fminf(fmaxf(dh0, -1.0f), 1.0f);
    hnew[n] = h[n] + dh0;
    float dh1 = 300.0f * nv.y / (areas[N + n] + 1e-6f);
    dh1 = fminf(fmaxf(dh1, -1.0f), 1.0f);
    hnew[N + n] = h[N + n] + dh1;
}

extern "C" void kernel_launch(void* const* d_in, const int* in_sizes, int n_in,
                              void* d_out, int out_size, void* d_ws, size_t ws_size,
                              hipStream_t stream)
{
    const float* h    = (const float*)d_in[0];
    const float* z    = (const float*)d_in[1];
    const int*   eidx = (const int*)  d_in[2];
    const float* rain = (const float*)d_in[4];
    const float* W1   = (const float*)d_in[5];
    const float* b1   = (const float*)d_in[6];
    const float* W2   = (const float*)d_in[7];
    const float* b2   = (const float*)d_in[8];
    const float* Wa   = (const float*)d_in[9];
    const float* ba   = (const float*)d_in[10];

    const int R = in_sizes[0];      // B*N
    const int E = in_sizes[3];
    const int N = R / 2;

    float* out_h     = (float*)d_out;
    float* out_flows = out_h + R;

    char* wsB = (char*)d_ws;
    size_t off = 0;
    auto take = [&](size_t bytes) -> char* {
        char* p = wsB + off;
        off = (off + bytes + 255) & ~(size_t)255;
        return p;
    };
    float*    packed   = (float*)   take((size_t)4 * N * 4);
    float*    areas    = (float*)   take((size_t)R * 4);
    float*    netT     = (float*)   take((size_t)2 * N * 4);
    unsigned* counters = (unsigned*)take(MAXBUK * 4);

    const int nbuk = (N + 255) >> 8;
    int cap = (int)(((size_t)2 * E / (nbuk > 0 ? nbuk : 1)) * 5 / 4 + 512);
    cap = (cap + 255) & ~255;
    unsigned* keysG = (unsigned*)take((size_t)nbuk * cap * 4);
    float2*   valsG = (float2*)  take((size_t)nbuk * cap * 8);
    const bool binned = (off <= ws_size) && (nbuk <= 256);

    pack_kernel<<<(N + 255) / 256, 256, 0, stream>>>(h, rain, packed, netT,
                                                     counters, N);
    // 2R threads: lane pairs (k-half parity) per row -> ceil(2R/256) blocks
    node_kernel<<<(2 * R + 255) / 256, 256, 0, stream>>>(z, W1, b1, W2, b2,
                                                         Wa, ba, packed,
                                                         areas, N, R);
    if (binned) {
        edge_bin_kernel<<<(E + E1_EPB - 1) / E1_EPB, E1_TPB, 0, stream>>>(
            eidx, packed, out_flows, keysG, valsG, counters, E, nbuk, cap);
        bucket_reduce_kernel<<<nbuk, 512, 0, stream>>>(
            keysG, valsG, counters, h, rain, areas, out_h, N, cap);
    } else {
        edge_kernel<<<(E + 255) / 256, 256, 0, stream>>>(eidx, packed,
                                                         out_flows, netT, E);
        update_kernel<<<(N + 255) / 256, 256, 0, stream>>>(h, netT, areas,
                                                           out_h, N);
    }
}

// Round 12
// 100.795 us; speedup vs baseline: 1.6975x; 1.0651x over previous
//
#include <hip/hip_runtime.h>
#include <math.h>

#define HIDDEN 128
#define MAXBUK 512
#define E1_TPB 256
#define E1_EPT 4
#define E1_EPB (E1_TPB * E1_EPT)   // 1024 edges per block
#define E1_PPB (E1_EPB * 2)        // 2048 pairs per block

// W1 LDS layout: [h 0..128)][68]  (64 cols used + 4 pad)
#define W1S_H_STRIDE 68

// ---- DPP quad helpers (VALU pipe) -----------------------------------------
__device__ __forceinline__ float dpp_xor1(float v) {
    int t = __builtin_amdgcn_update_dpp(0, __float_as_int(v),
                                        0xB1, 0xF, 0xF, true); // [1,0,3,2]
    return __int_as_float(t);
}
__device__ __forceinline__ float dpp_xor2(float v) {
    int t = __builtin_amdgcn_update_dpp(0, __float_as_int(v),
                                        0x4E, 0xF, 0xF, true); // [2,3,0,1]
    return __int_as_float(t);
}
__device__ __forceinline__ float quad_sum(float v) {
    float a = v + dpp_xor1(v);
    return a + dpp_xor2(a);
}

// fast gelu: 0.5x(1+erf(x/sqrt2)), A&S 7.1.26, |erf err|<=2e-7
__device__ __forceinline__ float gelu_fast(float x) {
    const float u  = x * 0.70710678118654752f;
    const float au = fabsf(u);
    const float t  = __builtin_amdgcn_rcpf(fmaf(0.3275911f, au, 1.0f));
    float poly = fmaf(1.061405429f, t, -1.453152027f);
    poly = fmaf(poly, t, 1.421413741f);
    poly = fmaf(poly, t, -0.284496736f);
    poly = fmaf(poly, t, 0.254829592f);
    poly *= t;
    const float e = __expf(-au * au);
    const float erfabs = fmaf(-poly, e, 1.0f);
    const float erfv = copysignf(erfabs, u);
    return 0.5f * x * (1.0f + erfv);
}

// ---------------------------------------------------------------------------
// Pack: packed[n] = (h0,h1,<c0>,<c1>); netT[n] = (rain0,rain1);
// block 0 zeros the bucket counters.
// ---------------------------------------------------------------------------
__global__ __launch_bounds__(256) void pack_kernel(
    const float* __restrict__ h, const float* __restrict__ rain,
    float* __restrict__ packed, float* __restrict__ netT,
    unsigned* __restrict__ counters, int N)
{
    const int tid = threadIdx.x;
    const int b = blockIdx.x;
    if (b == 0)
        for (int i = tid; i < MAXBUK; i += 256) counters[i] = 0u;
    const int n = b * blockDim.x + tid;
    if (n >= N) return;
    *reinterpret_cast<float2*>(&packed[4 * n]) = make_float2(h[n], h[N + n]);
    *reinterpret_cast<float2*>(&netT[2 * n])   = make_float2(rain[n], rain[N + n]);
}

// ---------------------------------------------------------------------------
// Node kernel v12: QUAD = 4 k-quarters own 4 rows.
//  - acc[4][16] = 64 VGPRs (v11-proven: accumulators stay resident, no remat)
//  - each W b128 LDS read reused across 4 rows -> W traffic 3.3GB -> 0.82GB
//  - z streamed float4, immediate use; quad lanes read SAME address
//    (broadcast coalesce, z fetched once)
//  - each lane has FULL h-sum for its 16 k's -> gelu needs no reduction;
//    only the scalar cf dot is quad-reduced (2 DPP)
//  - lane q writes row r0+q (all 4 lanes do useful epilogue work)
// ---------------------------------------------------------------------------
__global__ __launch_bounds__(256) void node_kernel(
    const float* __restrict__ z,     // [R][128]
    const float* __restrict__ W1,    // [128][64] row-major
    const float* __restrict__ b1, const float* __restrict__ W2,
    const float* __restrict__ b2, const float* __restrict__ Wa,
    const float* __restrict__ ba,
    float* __restrict__ packed, float* __restrict__ areas,
    int N, int R)
{
    __shared__ float w1s[128 * W1S_H_STRIDE];   // 34816 B
    __shared__ float b1s[64], w2s[64], was[128];

    const int tid = threadIdx.x;
    for (int i = tid; i < 128 * 64; i += 256) {
        const int hh = i >> 6, k = i & 63;
        w1s[hh * W1S_H_STRIDE + k] = W1[i];
    }
    if (tid < 64)       b1s[tid] = b1[tid];
    else if (tid < 128) w2s[tid - 64] = W2[tid - 64];
    else                was[tid - 128] = Wa[tid - 128];
    __syncthreads();

    const int q  = tid & 3;                          // k-quarter
    const int r0 = ((blockIdx.x * 256 + tid) >> 2) * 4;  // quad's 4 rows
    if (r0 >= R) return;                             // R % 4 == 0

    float acc[4][16];
#pragma unroll
    for (int r = 0; r < 4; ++r)
#pragma unroll
        for (int k = 0; k < 16; ++k) acc[r][k] = 0.f;
    float ad0 = 0.f, ad1 = 0.f, ad2 = 0.f, ad3 = 0.f;

    const float* __restrict__ z0 = z + (size_t)(r0 + 0) * HIDDEN;
    const float* __restrict__ z1 = z + (size_t)(r0 + 1) * HIDDEN;
    const float* __restrict__ z2 = z + (size_t)(r0 + 2) * HIDDEN;
    const float* __restrict__ z3 = z + (size_t)(r0 + 3) * HIDDEN;
    const float* __restrict__ wq = &w1s[q * 16];

#pragma unroll 2
    for (int i = 0; i < 32; ++i) {                   // h-quad
        const float4 zv0 = *reinterpret_cast<const float4*>(z0 + 4 * i);
        const float4 zv1 = *reinterpret_cast<const float4*>(z1 + 4 * i);
        const float4 zv2 = *reinterpret_cast<const float4*>(z2 + 4 * i);
        const float4 zv3 = *reinterpret_cast<const float4*>(z3 + 4 * i);
#pragma unroll
        for (int j = 0; j < 4; ++j) {
            const float a0 = (j == 0) ? zv0.x : (j == 1) ? zv0.y
                           : (j == 2) ? zv0.z : zv0.w;
            const float a1 = (j == 0) ? zv1.x : (j == 1) ? zv1.y
                           : (j == 2) ? zv1.z : zv1.w;
            const float a2 = (j == 0) ? zv2.x : (j == 1) ? zv2.y
                           : (j == 2) ? zv2.z : zv2.w;
            const float a3 = (j == 0) ? zv3.x : (j == 1) ? zv3.y
                           : (j == 2) ? zv3.z : zv3.w;
            const float* __restrict__ wrow = wq + (4 * i + j) * W1S_H_STRIDE;
#pragma unroll
            for (int kq = 0; kq < 4; ++kq) {
                const float4 w = *reinterpret_cast<const float4*>(wrow + 4 * kq);
                acc[0][4 * kq + 0] = fmaf(a0, w.x, acc[0][4 * kq + 0]);
                acc[1][4 * kq + 0] = fmaf(a1, w.x, acc[1][4 * kq + 0]);
                acc[2][4 * kq + 0] = fmaf(a2, w.x, acc[2][4 * kq + 0]);
                acc[3][4 * kq + 0] = fmaf(a3, w.x, acc[3][4 * kq + 0]);
                acc[0][4 * kq + 1] = fmaf(a0, w.y, acc[0][4 * kq + 1]);
                acc[1][4 * kq + 1] = fmaf(a1, w.y, acc[1][4 * kq + 1]);
                acc[2][4 * kq + 1] = fmaf(a2, w.y, acc[2][4 * kq + 1]);
                acc[3][4 * kq + 1] = fmaf(a3, w.y, acc[3][4 * kq + 1]);
                acc[0][4 * kq + 2] = fmaf(a0, w.z, acc[0][4 * kq + 2]);
                acc[1][4 * kq + 2] = fmaf(a1, w.z, acc[1][4 * kq + 2]);
                acc[2][4 * kq + 2] = fmaf(a2, w.z, acc[2][4 * kq + 2]);
                acc[3][4 * kq + 2] = fmaf(a3, w.z, acc[3][4 * kq + 2]);
                acc[0][4 * kq + 3] = fmaf(a0, w.w, acc[0][4 * kq + 3]);
                acc[1][4 * kq + 3] = fmaf(a1, w.w, acc[1][4 * kq + 3]);
                acc[2][4 * kq + 3] = fmaf(a2, w.w, acc[2][4 * kq + 3]);
                acc[3][4 * kq + 3] = fmaf(a3, w.w, acc[3][4 * kq + 3]);
            }
        }
        const float4 wa = *reinterpret_cast<const float4*>(&was[4 * i]);
        ad0 = fmaf(zv0.x, wa.x, ad0); ad0 = fmaf(zv0.y, wa.y, ad0);
        ad0 = fmaf(zv0.z, wa.z, ad0); ad0 = fmaf(zv0.w, wa.w, ad0);
        ad1 = fmaf(zv1.x, wa.x, ad1); ad1 = fmaf(zv1.y, wa.y, ad1);
        ad1 = fmaf(zv1.z, wa.z, ad1); ad1 = fmaf(zv1.w, wa.w, ad1);
        ad2 = fmaf(zv2.x, wa.x, ad2); ad2 = fmaf(zv2.y, wa.y, ad2);
        ad2 = fmaf(zv2.z, wa.z, ad2); ad2 = fmaf(zv2.w, wa.w, ad2);
        ad3 = fmaf(zv3.x, wa.x, ad3); ad3 = fmaf(zv3.y, wa.y, ad3);
        ad3 = fmaf(zv3.z, wa.z, ad3); ad3 = fmaf(zv3.w, wa.w, ad3);
    }

    // epilogue: per row, gelu over this lane's 16 k's, then quad-sum cf
    float cfq[4];
#pragma unroll
    for (int r = 0; r < 4; ++r) {
        float cf = 0.f;
#pragma unroll
        for (int kk = 0; kk < 16; ++kk) {
            const float x = acc[r][kk] + b1s[q * 16 + kk];
            cf = fmaf(gelu_fast(x), w2s[q * 16 + kk], cf);
        }
        cfq[r] = quad_sum(cf);          // full 64-k dot, same on all 4 lanes
    }

    // lane q writes row r0+q (static-select to avoid dynamic indexing)
    const float myCf = (q == 0) ? cfq[0] : (q == 1) ? cfq[1]
                     : (q == 2) ? cfq[2] : cfq[3];
    const float myAd = (q == 0) ? ad0 : (q == 1) ? ad1
                     : (q == 2) ? ad2 : ad3;
    const int row = r0 + q;
    const float cv   = 1.0f / (1.0f + expf(-(myCf + b2[0])));
    const float adv  = myAd + ba[0];
    const float area = fmaxf(adv, 0.f) + log1pf(expf(-fabsf(adv)));
    const int bb = (row >= N) ? 1 : 0;
    const int n = row - bb * N;
    packed[4 * n + 2 + bb] = cv;
    areas[row] = area;
}

// ---------------------------------------------------------------------------
// E1: per-edge flows + in-block counting-sort of (node, +/-f0,f1) pairs into
// per-bucket global segments (bucket = node>>8). ~196 int atomics per block.
// ---------------------------------------------------------------------------
__global__ __launch_bounds__(E1_TPB) void edge_bin_kernel(
    const int* __restrict__ eidx,      // [2][E]
    const float* __restrict__ packed,  // [N][4] = h0,h1,c0,c1
    float* __restrict__ flows,         // [2][E]
    unsigned* __restrict__ keysG,      // [nbuk][cap]
    float2* __restrict__ valsG,        // [nbuk][cap]
    unsigned* __restrict__ counters,   // [nbuk]
    int E, int nbuk, int cap)
{
    __shared__ unsigned hist[MAXBUK];
    __shared__ unsigned base[MAXBUK];
    __shared__ unsigned gbase[MAXBUK];
    __shared__ unsigned scan[E1_TPB];
    __shared__ unsigned skey[E1_PPB];
    __shared__ float2   sval[E1_PPB];

    const int tid = threadIdx.x;
    const int e0  = blockIdx.x * E1_EPB;

    for (int i = tid; i < nbuk; i += E1_TPB) hist[i] = 0;
    __syncthreads();

    unsigned mykey[2 * E1_EPT];
    unsigned myoff[2 * E1_EPT];
    float2   myval[2 * E1_EPT];

#pragma unroll
    for (int j = 0; j < E1_EPT; ++j) {
        const int e = e0 + j * E1_TPB + tid;
        unsigned kd = 0xFFFFFFFFu, ks = 0xFFFFFFFFu;
        float2 vd = make_float2(0.f, 0.f), vs = vd;
        if (e < E) {
            const int s = eidx[e];
            const int d = eidx[E + e];
            const float4 ps = *reinterpret_cast<const float4*>(&packed[4 * s]);
            const float4 pd = *reinterpret_cast<const float4*>(&packed[4 * d]);

            float dh = ps.x - pd.x;
            float sg = (dh > 0.f) ? 1.f : ((dh < 0.f) ? -1.f : 0.f);
            float f0 = ps.z * sg * sqrtf(fabsf(dh) + 1e-6f);
            f0 = fminf(fmaxf(f0, -10.0f), 10.0f);

            dh = ps.y - pd.y;
            sg = (dh > 0.f) ? 1.f : ((dh < 0.f) ? -1.f : 0.f);
            float f1 = ps.w * sg * sqrtf(fabsf(dh) + 1e-6f);
            f1 = fminf(fmaxf(f1, -10.0f), 10.0f);

            flows[e] = f0;
            flows[(size_t)E + e] = f1;

            kd = (unsigned)d; vd = make_float2(f0, f1);
            ks = (unsigned)s; vs = make_float2(-f0, -f1);
        }
        mykey[2 * j]     = kd; myval[2 * j]     = vd;
        mykey[2 * j + 1] = ks; myval[2 * j + 1] = vs;
        if (kd != 0xFFFFFFFFu) {
            myoff[2 * j]     = atomicAdd(&hist[kd >> 8], 1u);
            myoff[2 * j + 1] = atomicAdd(&hist[ks >> 8], 1u);
        }
    }
    __syncthreads();

    // Hillis-Steele inclusive scan of hist (nbuk <= 256)
    const unsigned hv = (tid < nbuk) ? hist[tid] : 0u;
    scan[tid] = hv;
    __syncthreads();
    for (int off = 1; off < E1_TPB; off <<= 1) {
        unsigned t = (tid >= off) ? scan[tid - off] : 0u;
        __syncthreads();
        scan[tid] += t;
        __syncthreads();
    }
    if (tid < nbuk) {
        base[tid] = scan[tid] - hv;
        if (hv > 0) gbase[tid] = atomicAdd(&counters[tid], hv);
    }
    __syncthreads();

#pragma unroll
    for (int j = 0; j < 2 * E1_EPT; ++j) {
        const unsigned k = mykey[j];
        if (k != 0xFFFFFFFFu) {
            const unsigned idx = base[k >> 8] + myoff[j];
            skey[idx] = k;
            sval[idx] = myval[j];
        }
    }
    __syncthreads();

    const int tot = 2 * min(E1_EPB, E - e0);
    for (int i = tid; i < tot; i += E1_TPB) {
        const unsigned k = skey[i];
        const unsigned bb = k >> 8;
        const unsigned pos = gbase[bb] + ((unsigned)i - base[bb]);
        if (pos < (unsigned)cap) {
            keysG[(size_t)bb * cap + pos] = k;
            valsG[(size_t)bb * cap + pos] = sval[i];
        }
    }
}

// ---------------------------------------------------------------------------
// E2: one block (512 thr) per bucket; FOUR LDS accumulator copies cut
// same-node atomic serialization. Fused h-update. No global f32 atomics.
// ---------------------------------------------------------------------------
__global__ __launch_bounds__(512) void bucket_reduce_kernel(
    const unsigned* __restrict__ keysG, const float2* __restrict__ valsG,
    const unsigned* __restrict__ counters,
    const float* __restrict__ h, const float* __restrict__ rain,
    const float* __restrict__ areas,
    float* __restrict__ hnew, int N, int cap)
{
    __shared__ float accx[4][256], accy[4][256];   // 8 KB
    const int tid = threadIdx.x;
    const int b = blockIdx.x;
    const int q = tid >> 7;                        // 4 groups of 128
    {
        float* fx = &accx[0][0];
        float* fy = &accy[0][0];
        fx[tid] = 0.f; fx[tid + 512] = 0.f;
        fy[tid] = 0.f; fy[tid + 512] = 0.f;
    }
    __syncthreads();

    const int cnt = min((int)counters[b], cap);
    const unsigned* __restrict__ sk = keysG + (size_t)b * cap;
    const float2*  __restrict__  sv = valsG + (size_t)b * cap;
    for (int i = tid; i < cnt; i += 512) {
        const unsigned k = sk[i];
        const float2 v2 = sv[i];
        const int loc = (int)(k & 255u);
        atomicAdd(&accx[q][loc], v2.x);
        atomicAdd(&accy[q][loc], v2.y);
    }
    __syncthreads();

    if (tid < 256) {
        const int n = (b << 8) + tid;
        if (n < N) {
            const float net0 = rain[n]     + ((accx[0][tid] + accx[1][tid])
                                           + (accx[2][tid] + accx[3][tid]));
            const float net1 = rain[N + n] + ((accy[0][tid] + accy[1][tid])
                                           + (accy[2][tid] + accy[3][tid]));
            float dh0 = 300.0f * net0 / (areas[n] + 1e-6f);
            dh0 = fminf(fmaxf(dh0, -1.0f), 1.0f);
            hnew[n] = h[n] + dh0;
            float dh1 = 300.0f * net1 / (areas[N + n] + 1e-6f);
            dh1 = fminf(fmaxf(dh1, -1.0f), 1.0f);
            hnew[N + n] = h[N + n] + dh1;
        }
    }
}

// ---------------------------------------------------------------------------
// Fallback path (ws too small): atomic edge + update kernels.
// ---------------------------------------------------------------------------
__global__ __launch_bounds__(256) void edge_kernel(
    const int* __restrict__ eidx, const float* __restrict__ packed,
    float* __restrict__ flows, float* __restrict__ netT, int E)
{
    const int e = blockIdx.x * blockDim.x + threadIdx.x;
    if (e >= E) return;
    const int s = eidx[e];
    const int d = eidx[E + e];
    const float4 ps = *reinterpret_cast<const float4*>(&packed[4 * s]);
    const float4 pd = *reinterpret_cast<const float4*>(&packed[4 * d]);
    {
        const float dh = ps.x - pd.x;
        const float sg = (dh > 0.f) ? 1.f : ((dh < 0.f) ? -1.f : 0.f);
        float f = ps.z * sg * sqrtf(fabsf(dh) + 1e-6f);
        f = fminf(fmaxf(f, -10.0f), 10.0f);
        flows[e] = f;
        unsafeAtomicAdd(&netT[2 * d + 0],  f);
        unsafeAtomicAdd(&netT[2 * s + 0], -f);
    }
    {
        const float dh = ps.y - pd.y;
        const float sg = (dh > 0.f) ? 1.f : ((dh < 0.f) ? -1.f : 0.f);
        float f = ps.w * sg * sqrtf(fabsf(dh) + 1e-6f);
        f = fminf(fmaxf(f, -10.0f), 10.0f);
        flows[(size_t)E + e] = f;
        unsafeAtomicAdd(&netT[2 * d + 1],  f);
        unsafeAtomicAdd(&netT[2 * s + 1], -f);
    }
}

__global__ __launch_bounds__(256) void update_kernel(
    const float* __restrict__ h, const float* __restrict__ netT,
    const float* __restrict__ areas, float* __restrict__ hnew, int N)
{
    const int n = blockIdx.x * blockDim.x + threadIdx.x;
    if (n >= N) return;
    const float2 nv = *reinterpret_cast<const float2*>(&netT[2 * n]);
    float dh0 = 300.0f * nv.x / (areas[n] + 1e-6f);
    dh0 = fminf(fmaxf(dh0, -1.0f), 1.0f);
    hnew[n] = h[n] + dh0;
    float dh1 = 300.0f * nv.y / (areas[N + n] + 1e-6f);
    dh1 = fminf(fmaxf(dh1, -1.0f), 1.0f);
    hnew[N + n] = h[N + n] + dh1;
}

extern "C" void kernel_launch(void* const* d_in, const int* in_sizes, int n_in,
                              void* d_out, int out_size, void* d_ws, size_t ws_size,
                              hipStream_t stream)
{
    const float* h    = (const float*)d_in[0];
    const float* z    = (const float*)d_in[1];
    const int*   eidx = (const int*)  d_in[2];
    const float* rain = (const float*)d_in[4];
    const float* W1   = (const float*)d_in[5];
    const float* b1   = (const float*)d_in[6];
    const float* W2   = (const float*)d_in[7];
    const float* b2   = (const float*)d_in[8];
    const float* Wa   = (const float*)d_in[9];
    const float* ba   = (const float*)d_in[10];

    const int R = in_sizes[0];      // B*N
    const int E = in_sizes[3];
    const int N = R / 2;

    float* out_h     = (float*)d_out;
    float* out_flows = out_h + R;

    char* wsB = (char*)d_ws;
    size_t off = 0;
    auto take = [&](size_t bytes) -> char* {
        char* p = wsB + off;
        off = (off + bytes + 255) & ~(size_t)255;
        return p;
    };
    float*    packed   = (float*)   take((size_t)4 * N * 4);
    float*    areas    = (float*)   take((size_t)R * 4);
    float*    netT     = (float*)   take((size_t)2 * N * 4);
    unsigned* counters = (unsigned*)take(MAXBUK * 4);

    const int nbuk = (N + 255) >> 8;
    int cap = (int)(((size_t)2 * E / (nbuk > 0 ? nbuk : 1)) * 5 / 4 + 512);
    cap = (cap + 255) & ~255;
    unsigned* keysG = (unsigned*)take((size_t)nbuk * cap * 4);
    float2*   valsG = (float2*)  take((size_t)nbuk * cap * 8);
    const bool binned = (off <= ws_size) && (nbuk <= 256);

    pack_kernel<<<(N + 255) / 256, 256, 0, stream>>>(h, rain, packed, netT,
                                                     counters, N);
    // R threads: quad (4 k-quarters) per 4 rows -> ceil(R/256) blocks
    node_kernel<<<(R + 255) / 256, 256, 0, stream>>>(z, W1, b1, W2, b2,
                                                     Wa, ba, packed,
                                                     areas, N, R);
    if (binned) {
        edge_bin_kernel<<<(E + E1_EPB - 1) / E1_EPB, E1_TPB, 0, stream>>>(
            eidx, packed, out_flows, keysG, valsG, counters, E, nbuk, cap);
        bucket_reduce_kernel<<<nbuk, 512, 0, stream>>>(
            keysG, valsG, counters, h, rain, areas, out_h, N, cap);
    } else {
        edge_kernel<<<(E + 255) / 256, 256, 0, stream>>>(eidx, packed,
                                                         out_flows, netT, E);
        update_kernel<<<(N + 255) / 256, 256, 0, stream>>>(h, netT, areas,
                                                           out_h, N);
    }
}